// Round 1
// baseline (33.070 us; speedup 1.0000x reference)
//
#include <hip/hip_runtime.h>
#include <math.h>

#define NQ 5
#define D 512
#define HALF_PI 1.57079632679489662f

// z_w = -sin(HALF_PI * tanh(pre_w)) * cos(q_params[w])
// zvals = {z1 z2 z3 z4, z0 z1, z0 z1 z2, z0 z1 z2 z3, z0 z1 z2 z3 z4}
// out   = zvals @ w_post.T + b_post

__global__ __launch_bounds__(256) void dressed_qnet_kernel(
    const float* __restrict__ x,        // (B, 512)
    const float* __restrict__ w_pre,    // (5, 512)
    const float* __restrict__ b_pre,    // (5,)
    const float* __restrict__ q_params, // (5,)
    const float* __restrict__ w_post,   // (2, 5)
    const float* __restrict__ b_post,   // (2,)
    float* __restrict__ out,            // (B, 2)
    int B)
{
    const int lane = threadIdx.x & 63;
    const int wave_in_block = threadIdx.x >> 6;
    const int waves_per_block = blockDim.x >> 6;
    const int wave_id = blockIdx.x * waves_per_block + wave_in_block;
    const int n_waves = gridDim.x * waves_per_block;

    // Per-lane register slice of w_pre: cols [lane*4, lane*4+4) and [256+lane*4, ...)
    float4 w0[NQ], w1[NQ];
#pragma unroll
    for (int q = 0; q < NQ; ++q) {
        w0[q] = *reinterpret_cast<const float4*>(w_pre + q * D + lane * 4);
        w1[q] = *reinterpret_cast<const float4*>(w_pre + q * D + 256 + lane * 4);
    }

    float bp[NQ], ct[NQ];
#pragma unroll
    for (int q = 0; q < NQ; ++q) {
        bp[q] = b_pre[q];
        ct[q] = __cosf(q_params[q]);   // row-invariant
    }
    float wp0[NQ], wp1[NQ];
#pragma unroll
    for (int q = 0; q < NQ; ++q) {
        wp0[q] = w_post[q];
        wp1[q] = w_post[NQ + q];
    }
    const float bpost0 = b_post[0];
    const float bpost1 = b_post[1];

    for (int row = wave_id; row < B; row += n_waves) {
        const float4* xr = reinterpret_cast<const float4*>(x + (size_t)row * D);
        const float4 x0 = xr[lane];
        const float4 x1 = xr[lane + 64];

        float acc[NQ];
#pragma unroll
        for (int q = 0; q < NQ; ++q) {
            float s;
            s  = x0.x * w0[q].x;
            s  = fmaf(x0.y, w0[q].y, s);
            s  = fmaf(x0.z, w0[q].z, s);
            s  = fmaf(x0.w, w0[q].w, s);
            s  = fmaf(x1.x, w1[q].x, s);
            s  = fmaf(x1.y, w1[q].y, s);
            s  = fmaf(x1.z, w1[q].z, s);
            s  = fmaf(x1.w, w1[q].w, s);
            acc[q] = s;
        }

        // 64-lane butterfly reduce; afterwards every lane holds the full dot.
#pragma unroll
        for (int q = 0; q < NQ; ++q) {
            float v = acc[q];
#pragma unroll
            for (int off = 32; off >= 1; off >>= 1)
                v += __shfl_xor(v, off, 64);
            acc[q] = v;
        }

        // Epilogue (uniform across lanes — no divergence cost).
        float z[NQ];
#pragma unroll
        for (int q = 0; q < NQ; ++q) {
            const float p = acc[q] + bp[q];
            // tanh(p) = 1 - 2/(exp(2p)+1)  (exact at +-inf, monotone, ~1e-7 rel err)
            const float e = __expf(2.0f * p);
            const float th = 1.0f - 2.0f / (e + 1.0f);
            z[q] = -__sinf(HALF_PI * th) * ct[q];   // |arg| <= pi/2: native sin safe
        }

        const float v1   = z[0] * z[1];
        const float z234 = z[2] * z[3] * z[4];
        const float v0   = z[1] * z234;
        const float v2   = v1 * z[2];
        const float v3   = v2 * z[3];
        const float v4   = v1 * z234;

        float o0 = bpost0, o1 = bpost1;
        o0 = fmaf(wp0[0], v0, o0); o1 = fmaf(wp1[0], v0, o1);
        o0 = fmaf(wp0[1], v1, o0); o1 = fmaf(wp1[1], v1, o1);
        o0 = fmaf(wp0[2], v2, o0); o1 = fmaf(wp1[2], v2, o1);
        o0 = fmaf(wp0[3], v3, o0); o1 = fmaf(wp1[3], v3, o1);
        o0 = fmaf(wp0[4], v4, o0); o1 = fmaf(wp1[4], v4, o1);

        if (lane == 0) {
            reinterpret_cast<float2*>(out)[row] = make_float2(o0, o1);
        }
    }
}

extern "C" void kernel_launch(void* const* d_in, const int* in_sizes, int n_in,
                              void* d_out, int out_size, void* d_ws, size_t ws_size,
                              hipStream_t stream) {
    const float* x        = (const float*)d_in[0];
    const float* w_pre    = (const float*)d_in[1];
    const float* b_pre    = (const float*)d_in[2];
    const float* q_params = (const float*)d_in[3];
    const float* w_post   = (const float*)d_in[4];
    const float* b_post   = (const float*)d_in[5];
    float* out = (float*)d_out;

    const int B = in_sizes[0] / D;   // 65536

    const int threads = 256;
    const int blocks = 2048;         // 8192 waves -> 8 rows per wave
    dressed_qnet_kernel<<<blocks, threads, 0, stream>>>(
        x, w_pre, b_pre, q_params, w_post, b_post, out, B);
}